// Round 3
// baseline (375.248 us; speedup 1.0000x reference)
//
#include <hip/hip_runtime.h>
#include <hip/hip_bf16.h>
#include <math.h>

#define Bsz 64
#define T 32
#define H 768
#define E 8
#define NB 2
#define DFF 3072
#define NBEAM (Bsz * NB)   // 128
#define NT8MAX 24          // max 8-beam tiles: worst case sum ceil(cnt_e/8) = 23

// d_out layout (floats):
#define OUT_BS 3145728
#define OUT_ER 3145856
#define OUT_BI 3145984
#define OUT_IL 3146112

// ws layout (float units):
#define WS_LOGITS 0                 // 3*512 chunked partial logits
#define WS_BEAMW  1536              // 128
#define WS_SORT   1664              // 128 int
#define WS_T8E    1792              // 24 int
#define WS_T8B    1832              // 24 int
#define WS_T8C    1872              // 24 int
#define WS_XBF    2048              // x bf16: 786432 floats
#define WS_HBF    (2048 + 786432)   // h bf16

typedef __attribute__((ext_vector_type(8))) short short8;
typedef __attribute__((ext_vector_type(4))) float f32x4;

__device__ __forceinline__ short8 cvt8(const float4 u, const float4 v) {
    union { short8 s; unsigned w[4]; } r;
    __hip_bfloat162 t;
    t = __float22bfloat162_rn(make_float2(u.x, u.y)); r.w[0] = *(unsigned*)&t;
    t = __float22bfloat162_rn(make_float2(u.z, u.w)); r.w[1] = *(unsigned*)&t;
    t = __float22bfloat162_rn(make_float2(v.x, v.y)); r.w[2] = *(unsigned*)&t;
    t = __float22bfloat162_rn(make_float2(v.z, v.w)); r.w[3] = *(unsigned*)&t;
    return r.s;
}

// async 16B global -> LDS (dest = uniform base + lane*16)
__device__ __forceinline__ void async16(void* lds, const void* g) {
    __builtin_amdgcn_global_load_lds(
        (const __attribute__((address_space(1))) void*)g,
        (__attribute__((address_space(3))) void*)lds, 16, 0, 0);
}

// ---------------------------------------------------------------------------
// x fp32 -> bf16, fully coalesced. 1536 blocks.
// ---------------------------------------------------------------------------
__global__ __launch_bounds__(256) void conv_x_kernel(
    const float* __restrict__ x, ushort* __restrict__ xb, int n4)
{
    const int i = blockIdx.x * 256 + threadIdx.x;
    if (i >= n4) return;
    const float4 v = ((const float4*)x)[i];
    __hip_bfloat162 t0 = __float22bfloat162_rn(make_float2(v.x, v.y));
    __hip_bfloat162 t1 = __float22bfloat162_rn(make_float2(v.z, v.w));
    ushort4 o;
    o.x = (*(unsigned*)&t0) & 0xffff; o.y = (*(unsigned*)&t0) >> 16;
    o.z = (*(unsigned*)&t1) & 0xffff; o.w = (*(unsigned*)&t1) >> 16;
    ((ushort4*)xb)[i] = o;
}

// ---------------------------------------------------------------------------
// Gate partial logits: grid (3 chunks, 64 batches).
// ---------------------------------------------------------------------------
__global__ __launch_bounds__(256) void gate_partial_kernel(
    const float* __restrict__ x, const float* __restrict__ gate_w,
    float* __restrict__ logits_part)
{
    __shared__ float part[4][E];
    const int chunk = blockIdx.x, b = blockIdx.y;
    const int tid = threadIdx.x, wv = tid >> 6, lane = tid & 63;
    const int c = chunk * 256 + tid;
    const float* xp = x + (size_t)b * T * H + c;
    float s = 0.f;
    #pragma unroll
    for (int t = 0; t < T; ++t) s += xp[t * H];
    const float avg = s * (1.0f / T);
    #pragma unroll
    for (int e = 0; e < E; ++e) {
        float p = avg * gate_w[e * H + c];
        #pragma unroll
        for (int off = 32; off; off >>= 1) p += __shfl_down(p, off, 64);
        if (lane == 0) part[wv][e] = p;
    }
    __syncthreads();
    if (tid < E) {
        float t = part[0][tid] + part[1][tid] + part[2][tid] + part[3][tid];
        logits_part[chunk * 512 + b * E + tid] = t;
    }
}

// ---------------------------------------------------------------------------
// Gating: softmax, top-2, outputs, importance loss, expert tables.
// 8-beam tiles placed into XCD-triples: the GEMM swizzle maps tile-triple
// {3c,3c+1,3c+2} onto XCD c, so placing expert e's tiles in triple e makes
// its W panel single-XCD. Overflow tiles spill round-robin into free slots.
// ---------------------------------------------------------------------------
__global__ __launch_bounds__(64) void gating_kernel(
    const float* __restrict__ logits_part, float* __restrict__ beam_w,
    int* __restrict__ sortb, int* __restrict__ t8e, int* __restrict__ t8b,
    int* __restrict__ t8c, float* __restrict__ dout)
{
    const int r = threadIdx.x;  // batch row 0..63
    float v[E];
    float mx = -1e30f;
    #pragma unroll
    for (int e = 0; e < E; ++e) {
        v[e] = logits_part[r * E + e] + logits_part[512 + r * E + e]
             + logits_part[1024 + r * E + e];
        mx = fmaxf(mx, v[e]);
    }
    float s = 0.f;
    #pragma unroll
    for (int e = 0; e < E; ++e) { v[e] = expf(v[e] - mx); s += v[e]; }
    const float inv = 1.0f / s;
    #pragma unroll
    for (int e = 0; e < E; ++e) v[e] *= inv;
    // top-2 (stable: lower index wins ties, matches jax.lax.top_k)
    float v0 = -1.f, v1 = -1.f; int i0 = 0, i1 = 0;
    #pragma unroll
    for (int e = 0; e < E; ++e) {
        if (v[e] > v0)      { v1 = v0; i1 = i0; v0 = v[e]; i0 = e; }
        else if (v[e] > v1) { v1 = v[e]; i1 = e; }
    }
    const int b0 = 2 * r, b1 = 2 * r + 1;
    dout[OUT_BS + b0] = v0;          dout[OUT_BS + b1] = v1;
    dout[OUT_ER + b0] = (float)i0;   dout[OUT_ER + b1] = (float)i1;
    dout[OUT_BI + b0] = (float)b0;   dout[OUT_BI + b1] = (float)b1;
    beam_w[b0] = v0;  beam_w[b1] = v1;
    // importance loss via 64-lane butterfly reductions
    float imp[E];
    #pragma unroll
    for (int e = 0; e < E; ++e) {
        float t = v[e];
        #pragma unroll
        for (int off = 1; off < 64; off <<= 1) t += __shfl_xor(t, off, 64);
        imp[e] = t;
    }
    if (r == 0) {
        float tot = 0.f;
        #pragma unroll
        for (int e = 0; e < E; ++e) tot += imp[e];
        const float mean = tot / E;
        float var = 0.f;
        #pragma unroll
        for (int e = 0; e < E; ++e) { float d = imp[e] - mean; var += d * d; }
        var /= (E - 1);
        dout[OUT_IL] = var / (mean * mean);
    }
    // expert-grouped sort via ballots (beams 2r even-mask, 2r+1 odd-mask)
    unsigned long long m0[E], m1[E];
    #pragma unroll
    for (int e = 0; e < E; ++e) {
        m0[e] = __ballot(i0 == e);
        m1[e] = __ballot(i1 == e);
    }
    int cnt[E], off[E];
    int a0 = 0;
    #pragma unroll
    for (int e = 0; e < E; ++e) {
        cnt[e] = __popcll(m0[e]) + __popcll(m1[e]);
        off[e] = a0; a0 += cnt[e];
    }
    const unsigned long long below = (r == 0) ? 0ull : ((1ull << r) - 1ull);
    const unsigned long long incl  = below | (1ull << r);
    const int pos0 = __popcll(m0[i0] & below) + __popcll(m1[i0] & below);
    const int pos1 = __popcll(m0[i1] & incl)  + __popcll(m1[i1] & below);
    sortb[off[i0] + pos0] = b0;
    sortb[off[i1] + pos1] = b1;
    // 8-beam tile table with XCD-triple placement (single thread, tiny)
    if (r == 0) {
        int tiles[E];
        int used[NT8MAX];
        for (int t = 0; t < NT8MAX; ++t) used[t] = 0;
        #pragma unroll
        for (int e = 0; e < E; ++e) tiles[e] = (cnt[e] + 7) >> 3;
        // primary placement: expert e -> slots 3e .. 3e+min(tiles,3)-1
        #pragma unroll
        for (int e = 0; e < E; ++e) {
            const int k = tiles[e] < 3 ? tiles[e] : 3;
            for (int i = 0; i < k; ++i) {
                const int sl = 3 * e + i;
                t8e[sl] = e; t8b[sl] = off[e] + 8 * i;
                const int rem = cnt[e] - 8 * i;
                t8c[sl] = rem < 8 ? rem : 8;
                used[sl] = 1;
            }
        }
        // free-slot list, round-robin across triples (keeps XCDs balanced)
        int fs[NT8MAX]; int nf = 0;
        for (int round = 0; round < 3; ++round)
            for (int c = 0; c < E; ++c) {
                const int sl = 3 * c + round;
                if (!used[sl]) fs[nf++] = sl;
            }
        int fp = 0;
        for (int e = 0; e < E; ++e)
            for (int i = 3; i < tiles[e]; ++i) {
                const int sl = fs[fp++];
                t8e[sl] = e; t8b[sl] = off[e] + 8 * i;
                const int rem = cnt[e] - 8 * i;
                t8c[sl] = rem < 8 ? rem : 8;
                used[sl] = 1;
            }
        for (int t = 0; t < NT8MAX; ++t) if (!used[t]) t8c[t] = 0;
    }
}

// ---------------------------------------------------------------------------
// LDS double-buffered MFMA GEMM, single barrier per k-tile.
// Tile: 256(m: 8 beams of one expert) x 64(n), Ktile=32.
// 4 waves in 2x2; wave tile 128m x 32n. acc[8][2] f32x4.
//
// XCD locality plan (the round-3 lever): blocks with hw%8==c run on XCD c
// (default round-robin dispatch). j=hw>>3 enumerates that XCD's work
// TILE-FASTEST: tile = 3c + j%3, strip = j/3. The 3 m-tiles sharing an
// expert's W n-strip panel are therefore ADJACENT and co-resident on one
// XCD, reading the same 16KB W k-window in near-lockstep -> W comes from
// LLC once per XCD, duplicates are same-XCD L2 hits (34.5 TB/s) instead of
// LLC (~7.3 TB/s, the measured round-0/1 service bound). A: GEMM1's x_bf
// (3.1MB) fits L2 outright; GEMM2's per-tile A k-window (3x16KB) is tiny
// and all 36 blocks/XCD are co-resident, so A re-reads across strips also
// hit L2.
//
// LDS swizzle: row=64B (32 k of bf16), 4 chunks of 16B. Stored chunk at
// pos p of row r is global chunk p ^ f(r), f(r) = (r>>1)&3. Per 16-lane
// phase of ds_read_b128 this covers all 8 16B-slots of the 128B bank
// window exactly twice -> 2-way (free). (f(r)=r&3 gave 4-way.)
// ---------------------------------------------------------------------------
template <int KTOT, bool DO_GELU>
__global__ __launch_bounds__(256, 2) void moe_ffn_mfma(
    const ushort* __restrict__ Abf, int a_div,
    const float* __restrict__ Wf32, int w_rows,
    const float* __restrict__ biasb,
    const int* __restrict__ sortb, const int* __restrict__ t8e,
    const int* __restrict__ t8b, const int* __restrict__ t8c,
    const float* __restrict__ beam_w,
    void* __restrict__ Obase)
{
    constexpr int KT = KTOT / 32;
    __shared__ __align__(16) ushort sA[2][256 * 32];   // 16 KB each
    __shared__ __align__(16) ushort sB[2][64 * 32];    // 4 KB each

    const int nx  = gridDim.x;
    const int hw  = blockIdx.y * nx + blockIdx.x;
    const int xcd = hw & 7;
    const int j   = hw >> 3;            // [0, 3*nx)
    const int tile  = 3 * xcd + j % 3;  // tile-fastest within XCD
    const int strip = j / 3;

    const int cnt  = t8c[tile];
    if (cnt == 0) return;
    const int e    = t8e[tile];
    const int base = t8b[tile];
    const int tid  = threadIdx.x;
    const int wv   = tid >> 6;
    const int lane = tid & 63;
    const int quad = lane >> 4;
    const int l16  = lane & 15;
    const int mh   = (wv & 1) * 128;
    const int nh   = (wv >> 1) * 32;
    const int n0   = strip * 64;

    int bm[8];
    #pragma unroll
    for (int s = 0; s < 8; ++s) bm[s] = sortb[base + (s < cnt ? s : cnt - 1)];

    // A DMA sources: wave does slots j=wv*4+jj; slot s=j*64+lane:
    // row=s>>2 (4 chunks of 8 bf16 per 32-k row), chunk c=(s&3)^((s>>3)&3)
    const ushort* aseg[4];
    #pragma unroll
    for (int jj = 0; jj < 4; ++jj) {
        const int s = (wv * 4 + jj) * 64 + lane;
        const int r = s >> 2;
        const int c = (s & 3) ^ ((s >> 3) & 3);
        aseg[jj] = Abf + (size_t)(bm[r >> 5] / a_div) * T * KTOT
                 + (size_t)(r & 31) * KTOT + c * 8;
    }
    // W slot: s = tid: row=s>>2 in [0,64), chunk c=(s&3)^((s>>3)&3)
    const float* wseg;
    int wslot;
    {
        const int r = tid >> 2;
        const int c = (tid & 3) ^ ((tid >> 3) & 3);
        wseg  = Wf32 + (size_t)e * w_rows * KTOT + (size_t)(n0 + r) * KTOT + c * 8;
        wslot = tid * 8;
    }

    // fragment read offsets: row r wants chunk quad at pos quad^f(r),
    // f(r)=(r>>1)&3; r = 16k + l16 -> f(r) = (l16>>1)&3
    const int fx = (l16 >> 1) & 3;
    int aoff[8], boff[2];
    #pragma unroll
    for (int mt = 0; mt < 8; ++mt)
        aoff[mt] = (mh + mt * 16 + l16) * 32 + ((quad ^ fx) * 8);
    #pragma unroll
    for (int nt = 0; nt < 2; ++nt)
        boff[nt] = (nh + nt * 16 + l16) * 32 + ((quad ^ fx) * 8);

    // prologue: tile 0 in flight
    float4 wr0 = *(const float4*)(wseg);
    float4 wr1 = *(const float4*)(wseg + 4);
    #pragma unroll
    for (int jj = 0; jj < 4; ++jj)
        async16((char*)sA[0] + (wv * 4 + jj) * 1024, aseg[jj]);

    f32x4 acc[8][2];
    #pragma unroll
    for (int mt = 0; mt < 8; ++mt) {
        acc[mt][0] = {0.f, 0.f, 0.f, 0.f};
        acc[mt][1] = {0.f, 0.f, 0.f, 0.f};
    }

    for (int kt = 0; kt < KT; ++kt) {
        const int p = kt & 1;
        // stage W(kt) into LDS (dependency waits its global loads)
        *(short8*)(sB[p] + wslot) = cvt8(wr0, wr1);
        __syncthreads();   // drains A-DMA(kt) + publishes W(kt)
        if (kt + 1 < KT) { // prefetch NEXT tile into other buffer
            const int kn = (kt + 1) * 32;
            #pragma unroll
            for (int jj = 0; jj < 4; ++jj)
                async16((char*)sA[1 - p] + (wv * 4 + jj) * 1024, aseg[jj] + kn);
            wr0 = *(const float4*)(wseg + kn);
            wr1 = *(const float4*)(wseg + kn + 4);
        }
        // compute(kt): one 16x16x32 MFMA per (mt,nt) covers the 32-k tile
        const short8 wf0 = *(const short8*)(sB[p] + boff[0]);
        const short8 wf1 = *(const short8*)(sB[p] + boff[1]);
        #pragma unroll
        for (int mt = 0; mt < 8; ++mt) {
            const short8 af = *(const short8*)(sA[p] + aoff[mt]);
            acc[mt][0] = __builtin_amdgcn_mfma_f32_16x16x32_bf16(
                af, wf0, acc[mt][0], 0, 0, 0);
            acc[mt][1] = __builtin_amdgcn_mfma_f32_16x16x32_bf16(
                af, wf1, acc[mt][1], 0, 0, 0);
        }
    }

    // epilogue
    #pragma unroll
    for (int nt = 0; nt < 2; ++nt) {
        const int n = n0 + nh + nt * 16 + l16;
        const float bias = biasb[(size_t)e * w_rows + n];
        #pragma unroll
        for (int mt = 0; mt < 8; ++mt) {
            const int rowb = mh + mt * 16 + quad * 4;
            const int s = rowb >> 5;
            if (s >= cnt) continue;
            const int b = bm[s];
            const float scale = DO_GELU ? 1.0f : beam_w[b];
            #pragma unroll
            for (int r = 0; r < 4; ++r) {
                const int t = (rowb + r) & 31;
                float vv = acc[mt][nt][r] + bias;
                const size_t idx = (size_t)b * T * w_rows + (size_t)t * w_rows + n;
                if (DO_GELU) {
                    vv = 0.5f * vv * (1.0f + erff(vv * 0.70710678118654752f));
                    ((__hip_bfloat16*)Obase)[idx] = __float2bfloat16(vv);
                } else {
                    ((float*)Obase)[idx] = vv * scale;
                }
            }
        }
    }
}

extern "C" void kernel_launch(void* const* d_in, const int* in_sizes, int n_in,
                              void* d_out, int out_size, void* d_ws, size_t ws_size,
                              hipStream_t stream)
{
    const float* x      = (const float*)d_in[0];
    const float* gate_w = (const float*)d_in[1];
    const float* w1     = (const float*)d_in[2];
    const float* b1     = (const float*)d_in[3];
    const float* w2     = (const float*)d_in[4];
    const float* b2     = (const float*)d_in[5];
    float* out = (float*)d_out;
    float* ws  = (float*)d_ws;

    float*  logits = ws + WS_LOGITS;
    float*  beam_w = ws + WS_BEAMW;
    int*    sortb  = (int*)(ws + WS_SORT);
    int*    t8e    = (int*)(ws + WS_T8E);
    int*    t8b    = (int*)(ws + WS_T8B);
    int*    t8c    = (int*)(ws + WS_T8C);
    ushort* x_bf   = (ushort*)(ws + WS_XBF);
    ushort* h_bf   = (ushort*)(ws + WS_HBF);

    conv_x_kernel<<<(Bsz * T * H / 4 + 255) / 256, 256, 0, stream>>>(
        x, x_bf, Bsz * T * H / 4);
    gate_partial_kernel<<<dim3(3, Bsz), 256, 0, stream>>>(x, gate_w, logits);
    gating_kernel<<<1, 64, 0, stream>>>(logits, beam_w, sortb, t8e, t8b, t8c, out);
    // GEMM1 + GELU: M=256/tile, N=DFF in 64-strips, K=768
    moe_ffn_mfma<H, true><<<dim3(DFF / 64, NT8MAX), 256, 0, stream>>>(
        x_bf, NB, w1, DFF, b1, sortb, t8e, t8b, t8c, beam_w, (void*)h_bf);
    // GEMM2 + scale: M=256/tile, N=H in 64-strips, K=3072
    moe_ffn_mfma<DFF, false><<<dim3(H / 64, NT8MAX), 256, 0, stream>>>(
        h_bf, 1, w2, H, b2, sortb, t8e, t8b, t8c, beam_w, out);
}

// Round 4
// 324.066 us; speedup vs baseline: 1.1579x; 1.1579x over previous
//
#include <hip/hip_runtime.h>
#include <hip/hip_bf16.h>
#include <math.h>

#define Bsz 64
#define T 32
#define H 768
#define E 8
#define NB 2
#define DFF 3072
#define NBEAM (Bsz * NB)   // 128
#define NT4MAX 40

// d_out layout (floats):
#define OUT_BS 3145728
#define OUT_ER 3145856
#define OUT_BI 3145984
#define OUT_IL 3146112

// ws layout (float units):
#define WS_LOGITS 0                 // 3*512 chunked partial logits
#define WS_BEAMW  1536              // 128
#define WS_SORT   1664              // 128 int
#define WS_T4E    1792              // 40 int
#define WS_T4B    1832              // 40 int
#define WS_T4C    1872              // 40 int
#define WS_XBF    2048              // x bf16: 786432 floats
#define WS_HBF    (2048 + 786432)   // h bf16: 6291456 floats

typedef __attribute__((ext_vector_type(8))) short short8;
typedef __attribute__((ext_vector_type(4))) float f32x4;

__device__ __forceinline__ short8 cvt8(const float4 u, const float4 v) {
    union { short8 s; unsigned w[4]; } r;
    __hip_bfloat162 t;
    t = __float22bfloat162_rn(make_float2(u.x, u.y)); r.w[0] = *(unsigned*)&t;
    t = __float22bfloat162_rn(make_float2(u.z, u.w)); r.w[1] = *(unsigned*)&t;
    t = __float22bfloat162_rn(make_float2(v.x, v.y)); r.w[2] = *(unsigned*)&t;
    t = __float22bfloat162_rn(make_float2(v.z, v.w)); r.w[3] = *(unsigned*)&t;
    return r.s;
}

// async 16B global -> LDS (dest = uniform base + lane*16)
__device__ __forceinline__ void async16(void* lds, const void* g) {
    __builtin_amdgcn_global_load_lds(
        (const __attribute__((address_space(1))) void*)g,
        (__attribute__((address_space(3))) void*)lds, 16, 0, 0);
}

// ---------------------------------------------------------------------------
// x fp32 -> bf16, fully coalesced. 1536 blocks.
// ---------------------------------------------------------------------------
__global__ __launch_bounds__(256) void conv_x_kernel(
    const float* __restrict__ x, ushort* __restrict__ xb, int n4)
{
    const int i = blockIdx.x * 256 + threadIdx.x;
    if (i >= n4) return;
    const float4 v = ((const float4*)x)[i];
    __hip_bfloat162 t0 = __float22bfloat162_rn(make_float2(v.x, v.y));
    __hip_bfloat162 t1 = __float22bfloat162_rn(make_float2(v.z, v.w));
    ushort4 o;
    o.x = (*(unsigned*)&t0) & 0xffff; o.y = (*(unsigned*)&t0) >> 16;
    o.z = (*(unsigned*)&t1) & 0xffff; o.w = (*(unsigned*)&t1) >> 16;
    ((ushort4*)xb)[i] = o;
}

// ---------------------------------------------------------------------------
// Gate partial logits: grid (3 chunks, 64 batches). Block handles 256 cols:
// column mean over T, dot with gate_w chunk for all 8 experts. Deterministic
// (no atomics): writes logits_part[chunk][b][e].
// ---------------------------------------------------------------------------
__global__ __launch_bounds__(256) void gate_partial_kernel(
    const float* __restrict__ x, const float* __restrict__ gate_w,
    float* __restrict__ logits_part)
{
    __shared__ float part[4][E];
    const int chunk = blockIdx.x, b = blockIdx.y;
    const int tid = threadIdx.x, wv = tid >> 6, lane = tid & 63;
    const int c = chunk * 256 + tid;
    const float* xp = x + (size_t)b * T * H + c;
    float s = 0.f;
    #pragma unroll
    for (int t = 0; t < T; ++t) s += xp[t * H];
    const float avg = s * (1.0f / T);
    #pragma unroll
    for (int e = 0; e < E; ++e) {
        float p = avg * gate_w[e * H + c];
        #pragma unroll
        for (int off = 32; off; off >>= 1) p += __shfl_down(p, off, 64);
        if (lane == 0) part[wv][e] = p;
    }
    __syncthreads();
    if (tid < E) {
        float t = part[0][tid] + part[1][tid] + part[2][tid] + part[3][tid];
        logits_part[chunk * 512 + b * E + tid] = t;
    }
}

// ---------------------------------------------------------------------------
// Gating: softmax, top-2, outputs, importance loss, expert tables.
// 1 block, 64 threads, FULLY parallel (ballot/popcount sort, shfl reduce).
// ---------------------------------------------------------------------------
__global__ __launch_bounds__(64) void gating_kernel(
    const float* __restrict__ logits_part, float* __restrict__ beam_w,
    int* __restrict__ sortb, int* __restrict__ t4e, int* __restrict__ t4b,
    int* __restrict__ t4c, float* __restrict__ dout)
{
    const int r = threadIdx.x;  // batch row 0..63
    float v[E];
    float mx = -1e30f;
    #pragma unroll
    for (int e = 0; e < E; ++e) {
        v[e] = logits_part[r * E + e] + logits_part[512 + r * E + e]
             + logits_part[1024 + r * E + e];
        mx = fmaxf(mx, v[e]);
    }
    float s = 0.f;
    #pragma unroll
    for (int e = 0; e < E; ++e) { v[e] = expf(v[e] - mx); s += v[e]; }
    const float inv = 1.0f / s;
    #pragma unroll
    for (int e = 0; e < E; ++e) v[e] *= inv;
    // top-2 (stable: lower index wins ties, matches jax.lax.top_k)
    float v0 = -1.f, v1 = -1.f; int i0 = 0, i1 = 0;
    #pragma unroll
    for (int e = 0; e < E; ++e) {
        if (v[e] > v0)      { v1 = v0; i1 = i0; v0 = v[e]; i0 = e; }
        else if (v[e] > v1) { v1 = v[e]; i1 = e; }
    }
    const int b0 = 2 * r, b1 = 2 * r + 1;
    dout[OUT_BS + b0] = v0;          dout[OUT_BS + b1] = v1;
    dout[OUT_ER + b0] = (float)i0;   dout[OUT_ER + b1] = (float)i1;
    dout[OUT_BI + b0] = (float)b0;   dout[OUT_BI + b1] = (float)b1;
    beam_w[b0] = v0;  beam_w[b1] = v1;
    // importance loss via 64-lane butterfly reductions
    float imp[E];
    #pragma unroll
    for (int e = 0; e < E; ++e) {
        float t = v[e];
        #pragma unroll
        for (int off = 1; off < 64; off <<= 1) t += __shfl_xor(t, off, 64);
        imp[e] = t;
    }
    if (r == 0) {
        float tot = 0.f;
        #pragma unroll
        for (int e = 0; e < E; ++e) tot += imp[e];
        const float mean = tot / E;
        float var = 0.f;
        #pragma unroll
        for (int e = 0; e < E; ++e) { float d = imp[e] - mean; var += d * d; }
        var /= (E - 1);
        dout[OUT_IL] = var / (mean * mean);
    }
    // expert-grouped sort via ballots (beams 2r even-mask, 2r+1 odd-mask)
    unsigned long long m0[E], m1[E];
    #pragma unroll
    for (int e = 0; e < E; ++e) {
        m0[e] = __ballot(i0 == e);
        m1[e] = __ballot(i1 == e);
    }
    int cnt[E], off[E];
    int a0 = 0;
    #pragma unroll
    for (int e = 0; e < E; ++e) {
        cnt[e] = __popcll(m0[e]) + __popcll(m1[e]);
        off[e] = a0; a0 += cnt[e];
    }
    const unsigned long long below = (r == 0) ? 0ull : ((1ull << r) - 1ull);
    const unsigned long long incl  = below | (1ull << r);
    const int pos0 = __popcll(m0[i0] & below) + __popcll(m1[i0] & below);
    const int pos1 = __popcll(m0[i1] & incl)  + __popcll(m1[i1] & below);
    sortb[off[i0] + pos0] = b0;
    sortb[off[i1] + pos1] = b1;
    // 4-beam tile table
    int tb[E]; int tc = 0;
    #pragma unroll
    for (int e = 0; e < E; ++e) { tb[e] = tc; tc += (cnt[e] + 3) >> 2; }
    if (r < E) {
        const int e = r;
        int j = tb[e];
        for (int i = 0; i < cnt[e]; i += 4, ++j) {
            t4e[j] = e;
            t4b[j] = off[e] + i;
            t4c[j] = (cnt[e] - i < 4) ? (cnt[e] - i) : 4;
        }
    }
    for (int t = tc + r; t < NT4MAX; t += 64) t4c[t] = 0;
}

// ---------------------------------------------------------------------------
// LDS double-buffered MFMA GEMM, single barrier per k-tile. (= round-1
// structure, best measured.) Tile: 128m x NTILE n, Ktile=64, 4 waves 2x2.
//
// NSLICE: split-K factor. Evidence R0/R1/R3: time tracks resident-wave
// count (Little's law: one k-tile of loads in flight per block), NOT
// request tier (R1: HBM-20% = flat) and NOT HBM volume (R3: fetch -64%,
// time +47% at half occupancy). Split-K doubles blocks & halves the
// per-block serial chain at EXACTLY constant request volume -> dominant
// move under either candidate model.
// NSLICE=2: both slices atomicAdd into zeroed output; slice0 adds bias.
// 2 addends commute bitwise in IEEE -> deterministic.
// ---------------------------------------------------------------------------
template <int KTOT, int NTILE, bool DO_GELU, int NSLICE>
__global__ __launch_bounds__(256, 2) void moe_ffn_mfma(
    const ushort* __restrict__ Abf, int a_div,
    const float* __restrict__ Wf32, int w_rows,
    const float* __restrict__ biasb,
    const int* __restrict__ sortb, const int* __restrict__ t4e,
    const int* __restrict__ t4b, const int* __restrict__ t4c,
    const float* __restrict__ beam_w,
    void* __restrict__ Obase)
{
    constexpr int KSPAN = KTOT / NSLICE;
    constexpr int KT = KSPAN / 64;
    constexpr int WF = NTILE / 32;      // n-frags per wave / W slots per thread
    __shared__ __align__(16) ushort sA[2][128 * 64];
    __shared__ __align__(16) ushort sB[2][NTILE * 64];

    // XCD-chunked bijective swizzle over (tile fastest, strip, kslice).
    const int nx  = gridDim.x;
    const int nwg = nx * NT4MAX * NSLICE;
    const int hw  = blockIdx.y * nx + blockIdx.x;
    const int q8  = nwg >> 3;
    const int lid = (hw & 7) * q8 + (hw >> 3);
    const int tile  = lid % NT4MAX;
    const int rr    = lid / NT4MAX;            // [0, nx*NSLICE)
    const int strip = (NSLICE == 1) ? rr : (rr % nx);
    const int k0    = (NSLICE == 1) ? 0 : (rr / nx) * KSPAN;

    const int cnt  = t4c[tile];
    if (cnt == 0) return;
    const int e    = t4e[tile];
    const int base = t4b[tile];
    const int tid  = threadIdx.x;
    const int wv   = tid >> 6;
    const int lane = tid & 63;
    const int quad = lane >> 4;
    const int l16  = lane & 15;
    const int mh   = (wv & 1) * 64;
    const int nh   = (wv >> 1) * (NTILE / 2);
    const int n0   = strip * NTILE;

    int bm[4];
    #pragma unroll
    for (int s = 0; s < 4; ++s) bm[s] = sortb[base + (s < cnt ? s : cnt - 1)];

    // A DMA sources: wave does slots j=wv*4+jj; slot s=j*64+lane:
    // row=s>>3, pos=s&7, source chunk c = pos^(row&7)
    const ushort* aseg[4];
    #pragma unroll
    for (int jj = 0; jj < 4; ++jj) {
        const int s = (wv * 4 + jj) * 64 + lane;
        const int r = s >> 3;
        const int c = (s & 7) ^ (r & 7);
        aseg[jj] = Abf + (size_t)(bm[r >> 5] / a_div) * T * KTOT
                 + (size_t)(r & 31) * KTOT + c * 8 + k0;
    }
    // W slots: s=jj*256+tid: row=s>>3, c=(s&7)^(row&7)
    const float* wseg[WF];
    int wslot[WF];
    #pragma unroll
    for (int jj = 0; jj < WF; ++jj) {
        const int s = jj * 256 + tid;
        const int r = s >> 3;
        const int c = (s & 7) ^ (r & 7);
        wseg[jj] = Wf32 + (size_t)e * w_rows * KTOT + (size_t)(n0 + r) * KTOT
                 + c * 8 + k0;
        wslot[jj] = s * 8;
    }

    int arow[4], ar7[4], brow[WF], br7[WF];
    #pragma unroll
    for (int mt = 0; mt < 4; ++mt) {
        const int r = mh + mt * 16 + l16;
        arow[mt] = r * 64; ar7[mt] = r & 7;
    }
    #pragma unroll
    for (int nt = 0; nt < WF; ++nt) {
        const int r = nh + nt * 16 + l16;
        brow[nt] = r * 64; br7[nt] = r & 7;
    }

    // prologue: tile 0 in flight
    float4 wr[WF][2];
    #pragma unroll
    for (int jj = 0; jj < WF; ++jj) {
        wr[jj][0] = *(const float4*)(wseg[jj]);
        wr[jj][1] = *(const float4*)(wseg[jj] + 4);
    }
    #pragma unroll
    for (int jj = 0; jj < 4; ++jj)
        async16((char*)sA[0] + (wv * 4 + jj) * 1024, aseg[jj]);

    f32x4 acc[4][WF];
    #pragma unroll
    for (int mt = 0; mt < 4; ++mt)
        #pragma unroll
        for (int nt = 0; nt < WF; ++nt) acc[mt][nt] = {0.f, 0.f, 0.f, 0.f};

    for (int kt = 0; kt < KT; ++kt) {
        const int p = kt & 1;
        // stage W(kt) into LDS (waits its global loads via dependency)
        #pragma unroll
        for (int jj = 0; jj < WF; ++jj)
            *(short8*)(sB[p] + wslot[jj]) = cvt8(wr[jj][0], wr[jj][1]);
        __syncthreads();   // drains A-DMA(kt) + publishes W(kt)
        if (kt + 1 < KT) { // prefetch NEXT tile into other buffer (hidden by compute)
            const int kn = (kt + 1) * 64;
            #pragma unroll
            for (int jj = 0; jj < 4; ++jj)
                async16((char*)sA[1 - p] + (wv * 4 + jj) * 1024, aseg[jj] + kn);
            #pragma unroll
            for (int jj = 0; jj < WF; ++jj) {
                wr[jj][0] = *(const float4*)(wseg[jj] + kn);
                wr[jj][1] = *(const float4*)(wseg[jj] + kn + 4);
            }
        }
        // compute(kt)
        #pragma unroll
        for (int ks = 0; ks < 2; ++ks) {
            short8 af[4], wf[WF];
            #pragma unroll
            for (int mt = 0; mt < 4; ++mt)
                af[mt] = *(const short8*)(sA[p] + arow[mt] + (((ks * 4 + quad) ^ ar7[mt]) * 8));
            #pragma unroll
            for (int nt = 0; nt < WF; ++nt)
                wf[nt] = *(const short8*)(sB[p] + brow[nt] + (((ks * 4 + quad) ^ br7[nt]) * 8));
            #pragma unroll
            for (int mt = 0; mt < 4; ++mt)
                #pragma unroll
                for (int nt = 0; nt < WF; ++nt)
                    acc[mt][nt] = __builtin_amdgcn_mfma_f32_16x16x32_bf16(
                        af[mt], wf[nt], acc[mt][nt], 0, 0, 0);
        }
    }

    // epilogue
    #pragma unroll
    for (int nt = 0; nt < WF; ++nt) {
        const int n = n0 + nh + nt * 16 + l16;
        const float bias = biasb[(size_t)e * w_rows + n];
        #pragma unroll
        for (int mt = 0; mt < 4; ++mt) {
            const int rowb = mh + mt * 16 + quad * 4;
            const int s = rowb >> 5;
            if (s >= cnt) continue;
            const int b = bm[s];
            const float scale = DO_GELU ? 1.0f : beam_w[b];
            #pragma unroll
            for (int r = 0; r < 4; ++r) {
                const int t = (rowb + r) & 31;
                const size_t idx = (size_t)b * T * w_rows + (size_t)t * w_rows + n;
                if (DO_GELU) {
                    float vv = acc[mt][nt][r] + bias;
                    vv = 0.5f * vv * (1.0f + erff(vv * 0.70710678118654752f));
                    ((__hip_bfloat16*)Obase)[idx] = __float2bfloat16(vv);
                } else {
                    // split-K: both slices atomically accumulate; slice 0
                    // carries the bias. 2 addends -> order-independent
                    // bitwise (IEEE add commutes) -> deterministic.
                    float vv = acc[mt][nt][r] + ((k0 == 0) ? bias : 0.f);
                    atomicAdd((float*)Obase + idx, vv * scale);
                }
            }
        }
    }
}

extern "C" void kernel_launch(void* const* d_in, const int* in_sizes, int n_in,
                              void* d_out, int out_size, void* d_ws, size_t ws_size,
                              hipStream_t stream)
{
    const float* x      = (const float*)d_in[0];
    const float* gate_w = (const float*)d_in[1];
    const float* w1     = (const float*)d_in[2];
    const float* b1     = (const float*)d_in[3];
    const float* w2     = (const float*)d_in[4];
    const float* b2     = (const float*)d_in[5];
    float* out = (float*)d_out;
    float* ws  = (float*)d_ws;

    float*  logits = ws + WS_LOGITS;
    float*  beam_w = ws + WS_BEAMW;
    int*    sortb  = (int*)(ws + WS_SORT);
    int*    t4e    = (int*)(ws + WS_T4E);
    int*    t4b    = (int*)(ws + WS_T4B);
    int*    t4c    = (int*)(ws + WS_T4C);
    ushort* x_bf   = (ushort*)(ws + WS_XBF);
    ushort* h_bf   = (ushort*)(ws + WS_HBF);

    // zero the main output region (split-K GEMM2 accumulates atomically)
    hipMemsetAsync(out, 0, (size_t)NBEAM * T * H * sizeof(float), stream);

    conv_x_kernel<<<(Bsz * T * H / 4 + 255) / 256, 256, 0, stream>>>(
        x, x_bf, Bsz * T * H / 4);
    gate_partial_kernel<<<dim3(3, Bsz), 256, 0, stream>>>(x, gate_w, logits);
    gating_kernel<<<1, 64, 0, stream>>>(logits, beam_w, sortb, t4e, t4b, t4c, out);
    // GEMM1 + GELU: M=128/tile, N=DFF in 128-strips, K=768
    moe_ffn_mfma<H, 128, true, 1><<<dim3(DFF / 128, NT4MAX), 256, 0, stream>>>(
        x_bf, NB, w1, DFF, b1, sortb, t4e, t4b, t4c, beam_w, (void*)h_bf);
    // GEMM2 + scale: M=128/tile, N=H in 64-strips, K=3072 split 2x1536
    moe_ffn_mfma<DFF, 64, false, 2><<<dim3(H / 64, NT4MAX * 2), 256, 0, stream>>>(
        h_bf, 1, w2, H, b2, sortb, t4e, t4b, t4c, beam_w, out);
}

// Round 5
// 316.397 us; speedup vs baseline: 1.1860x; 1.0242x over previous
//
#include <hip/hip_runtime.h>
#include <hip/hip_bf16.h>
#include <math.h>

#define Bsz 64
#define T 32
#define H 768
#define E 8
#define NB 2
#define DFF 3072
#define NBEAM (Bsz * NB)   // 128
#define NT8MAX 24          // max 8-beam tiles: worst case sum ceil(cnt_e/8) = 23

// d_out layout (floats):
#define OUT_BS 3145728
#define OUT_ER 3145856
#define OUT_BI 3145984
#define OUT_IL 3146112

// ws layout (float units):
#define WS_LOGITS 0                 // 3*512 chunked partial logits
#define WS_BEAMW  1536              // 128
#define WS_SORT   1664              // 128 int
#define WS_T8E    1792              // 24 int
#define WS_T8B    1832              // 24 int
#define WS_T8C    1872              // 24 int
#define WS_XBF    2048              // x bf16: 786432 floats
#define WS_HBF    (2048 + 786432)   // h bf16: 6291456 floats

typedef __attribute__((ext_vector_type(8))) short short8;
typedef __attribute__((ext_vector_type(4))) float f32x4;

__device__ __forceinline__ short8 cvt8(const float4 u, const float4 v) {
    union { short8 s; unsigned w[4]; } r;
    __hip_bfloat162 t;
    t = __float22bfloat162_rn(make_float2(u.x, u.y)); r.w[0] = *(unsigned*)&t;
    t = __float22bfloat162_rn(make_float2(u.z, u.w)); r.w[1] = *(unsigned*)&t;
    t = __float22bfloat162_rn(make_float2(v.x, v.y)); r.w[2] = *(unsigned*)&t;
    t = __float22bfloat162_rn(make_float2(v.z, v.w)); r.w[3] = *(unsigned*)&t;
    return r.s;
}

// async 16B global -> LDS (dest = uniform base + lane*16)
__device__ __forceinline__ void async16(void* lds, const void* g) {
    __builtin_amdgcn_global_load_lds(
        (const __attribute__((address_space(1))) void*)g,
        (__attribute__((address_space(3))) void*)lds, 16, 0, 0);
}

// ---------------------------------------------------------------------------
// Fused gate partials + x fp32->bf16. Grid (3 chunks, 64 batches); the grid
// covers every (b, t, c) of x exactly once, so this kernel also emits x_bf
// (saves the separate conv kernel and a second full read of x).
// Sum order over t is element-by-element, identical to the old kernel.
// ---------------------------------------------------------------------------
__global__ __launch_bounds__(256) void gate_conv_kernel(
    const float* __restrict__ x, const float* __restrict__ gate_w,
    ushort* __restrict__ xb, float* __restrict__ logits_part)
{
    __shared__ float part[4][E];
    const int chunk = blockIdx.x, b = blockIdx.y;
    const int tid = threadIdx.x, wv = tid >> 6, lane = tid & 63;
    const int c = chunk * 256 + tid;
    const float* xp = x + (size_t)b * T * H + c;
    ushort* xo = xb + (size_t)b * T * H + c;
    float s = 0.f;
    #pragma unroll
    for (int t = 0; t < T; t += 2) {
        const float f0 = xp[t * H];
        const float f1 = xp[(t + 1) * H];
        s += f0; s += f1;
        __hip_bfloat162 t2 = __float22bfloat162_rn(make_float2(f0, f1));
        const unsigned u = *(const unsigned*)&t2;
        xo[t * H]       = (ushort)(u & 0xffff);
        xo[(t + 1) * H] = (ushort)(u >> 16);
    }
    const float avg = s * (1.0f / T);
    #pragma unroll
    for (int e = 0; e < E; ++e) {
        float p = avg * gate_w[e * H + c];
        #pragma unroll
        for (int off = 32; off; off >>= 1) p += __shfl_down(p, off, 64);
        if (lane == 0) part[wv][e] = p;
    }
    __syncthreads();
    if (tid < E) {
        float t = part[0][tid] + part[1][tid] + part[2][tid] + part[3][tid];
        logits_part[chunk * 512 + b * E + tid] = t;
    }
}

// ---------------------------------------------------------------------------
// Gating: softmax, top-2, outputs, importance loss, 8-beam expert tables.
// (t8 table construction correctness-proven in the round-3 run.)
// ---------------------------------------------------------------------------
__global__ __launch_bounds__(64) void gating_kernel(
    const float* __restrict__ logits_part, float* __restrict__ beam_w,
    int* __restrict__ sortb, int* __restrict__ t8e, int* __restrict__ t8b,
    int* __restrict__ t8c, float* __restrict__ dout)
{
    const int r = threadIdx.x;  // batch row 0..63
    float v[E];
    float mx = -1e30f;
    #pragma unroll
    for (int e = 0; e < E; ++e) {
        v[e] = logits_part[r * E + e] + logits_part[512 + r * E + e]
             + logits_part[1024 + r * E + e];
        mx = fmaxf(mx, v[e]);
    }
    float s = 0.f;
    #pragma unroll
    for (int e = 0; e < E; ++e) { v[e] = expf(v[e] - mx); s += v[e]; }
    const float inv = 1.0f / s;
    #pragma unroll
    for (int e = 0; e < E; ++e) v[e] *= inv;
    // top-2 (stable: lower index wins ties, matches jax.lax.top_k)
    float v0 = -1.f, v1 = -1.f; int i0 = 0, i1 = 0;
    #pragma unroll
    for (int e = 0; e < E; ++e) {
        if (v[e] > v0)      { v1 = v0; i1 = i0; v0 = v[e]; i0 = e; }
        else if (v[e] > v1) { v1 = v[e]; i1 = e; }
    }
    const int b0 = 2 * r, b1 = 2 * r + 1;
    dout[OUT_BS + b0] = v0;          dout[OUT_BS + b1] = v1;
    dout[OUT_ER + b0] = (float)i0;   dout[OUT_ER + b1] = (float)i1;
    dout[OUT_BI + b0] = (float)b0;   dout[OUT_BI + b1] = (float)b1;
    beam_w[b0] = v0;  beam_w[b1] = v1;
    // importance loss via 64-lane butterfly reductions
    float imp[E];
    #pragma unroll
    for (int e = 0; e < E; ++e) {
        float t = v[e];
        #pragma unroll
        for (int off = 1; off < 64; off <<= 1) t += __shfl_xor(t, off, 64);
        imp[e] = t;
    }
    if (r == 0) {
        float tot = 0.f;
        #pragma unroll
        for (int e = 0; e < E; ++e) tot += imp[e];
        const float mean = tot / E;
        float var = 0.f;
        #pragma unroll
        for (int e = 0; e < E; ++e) { float d = imp[e] - mean; var += d * d; }
        var /= (E - 1);
        dout[OUT_IL] = var / (mean * mean);
    }
    // expert-grouped sort via ballots (beams 2r even-mask, 2r+1 odd-mask)
    unsigned long long m0[E], m1[E];
    #pragma unroll
    for (int e = 0; e < E; ++e) {
        m0[e] = __ballot(i0 == e);
        m1[e] = __ballot(i1 == e);
    }
    int cnt[E], off[E];
    int a0 = 0;
    #pragma unroll
    for (int e = 0; e < E; ++e) {
        cnt[e] = __popcll(m0[e]) + __popcll(m1[e]);
        off[e] = a0; a0 += cnt[e];
    }
    const unsigned long long below = (r == 0) ? 0ull : ((1ull << r) - 1ull);
    const unsigned long long incl  = below | (1ull << r);
    const int pos0 = __popcll(m0[i0] & below) + __popcll(m1[i0] & below);
    const int pos1 = __popcll(m0[i1] & incl)  + __popcll(m1[i1] & below);
    sortb[off[i0] + pos0] = b0;
    sortb[off[i1] + pos1] = b1;
    // 8-beam tile table (single thread, tiny)
    if (r == 0) {
        int tiles[E];
        int used[NT8MAX];
        for (int t = 0; t < NT8MAX; ++t) used[t] = 0;
        #pragma unroll
        for (int e = 0; e < E; ++e) tiles[e] = (cnt[e] + 7) >> 3;
        // primary placement: expert e -> slots 3e .. 3e+min(tiles,3)-1
        #pragma unroll
        for (int e = 0; e < E; ++e) {
            const int k = tiles[e] < 3 ? tiles[e] : 3;
            for (int i = 0; i < k; ++i) {
                const int sl = 3 * e + i;
                t8e[sl] = e; t8b[sl] = off[e] + 8 * i;
                const int rem = cnt[e] - 8 * i;
                t8c[sl] = rem < 8 ? rem : 8;
                used[sl] = 1;
            }
        }
        // free-slot list, round-robin (keeps load balanced)
        int fs[NT8MAX]; int nf = 0;
        for (int round = 0; round < 3; ++round)
            for (int c = 0; c < E; ++c) {
                const int sl = 3 * c + round;
                if (!used[sl]) fs[nf++] = sl;
            }
        int fp = 0;
        for (int e = 0; e < E; ++e)
            for (int i = 3; i < tiles[e]; ++i) {
                const int sl = fs[fp++];
                t8e[sl] = e; t8b[sl] = off[e] + 8 * i;
                const int rem = cnt[e] - 8 * i;
                t8c[sl] = rem < 8 ? rem : 8;
                used[sl] = 1;
            }
        for (int t = 0; t < NT8MAX; ++t) if (!used[t]) t8c[t] = 0;
    }
}

// ---------------------------------------------------------------------------
// LDS double-buffered MFMA GEMM, single barrier per k-tile.
// Tile: 256m (8 beams) x 128n, KTILE=32. 4 waves 2x2; wave = 128m x 64n.
// LDS 48 KB (sA 2x16K + sB 2x8K).
//
// Evidence-driven geometry (R0-R4): time = requested-bytes / ~8 TB/s once
// active blocks >= ~400 (cache-hierarchy service ceiling; tier placement
// and extra occupancy are irrelevant: R1 flat at -20% HBM, R4 flat at
// +2x blocks). So: M=256 halves W-requests (tiles ~34->~17), NTILE=128
// halves A-requests, and GEMM2 split-K=4 restores active blocks to
// ~17x6x4 ~= 408 (R3 showed ~200 active drops service to 5 TB/s).
// Per-block per-iter request = 16KB A + 16KB W, same as proven R1 loop.
//
// LDS swizzle (R3-proven, 0 conflicts): row = 64B = 4 chunks of 16B;
// chunk stored at pos p holds global chunk p ^ f(r), f(r) = (r>>1)&3.
// NSLICE>1: slices atomicAdd into zeroed output; slice k0==0 adds bias.
// ---------------------------------------------------------------------------
template <int KTOT, int NTILE, bool DO_GELU, int NSLICE>
__global__ __launch_bounds__(256, 2) void moe_ffn_mfma(
    const ushort* __restrict__ Abf, int a_div,
    const float* __restrict__ Wf32, int w_rows,
    const float* __restrict__ biasb,
    const int* __restrict__ sortb, const int* __restrict__ t8e,
    const int* __restrict__ t8b, const int* __restrict__ t8c,
    const float* __restrict__ beam_w,
    void* __restrict__ Obase)
{
    constexpr int KSPAN = KTOT / NSLICE;
    constexpr int KT    = KSPAN / 32;
    constexpr int NFRAG = NTILE / 32;   // n-frags per wave (wave n-span/16)
    constexpr int WSLOT = NTILE / 64;   // W 16B-slots per thread
    __shared__ __align__(16) ushort sA[2][256 * 32];     // 16 KB each
    __shared__ __align__(16) ushort sB[2][NTILE * 32];   // 8 KB each @128

    // XCD-chunked bijective swizzle; nwg % 8 == 0 (576 for both launches).
    const int nx  = gridDim.x;
    const int nwg = nx * gridDim.y;
    const int hw  = blockIdx.y * nx + blockIdx.x;
    const int q8  = nwg >> 3;
    const int lid = (hw & 7) * q8 + (hw >> 3);
    const int tile  = lid % NT8MAX;
    const int rr    = lid / NT8MAX;
    const int strip = rr % nx;
    const int k0    = (rr / nx) * KSPAN;

    const int cnt  = t8c[tile];
    if (cnt == 0) return;
    const int e    = t8e[tile];
    const int base = t8b[tile];
    const int tid  = threadIdx.x;
    const int wv   = tid >> 6;
    const int lane = tid & 63;
    const int quad = lane >> 4;
    const int l16  = lane & 15;
    const int mh   = (wv & 1) * 128;
    const int nh   = (wv >> 1) * (NTILE / 2);
    const int n0   = strip * NTILE;

    int bm[8];
    #pragma unroll
    for (int s = 0; s < 8; ++s) bm[s] = sortb[base + (s < cnt ? s : cnt - 1)];

    // A DMA sources: wave does slots j=wv*4+jj; slot s=j*64+lane:
    // row=s>>2 (4 chunks of 8 bf16 per 32-k row), chunk c=(s&3)^((s>>3)&3)
    const ushort* aseg[4];
    #pragma unroll
    for (int jj = 0; jj < 4; ++jj) {
        const int s = (wv * 4 + jj) * 64 + lane;
        const int r = s >> 2;
        const int c = (s & 3) ^ ((s >> 3) & 3);
        aseg[jj] = Abf + (size_t)(bm[r >> 5] / a_div) * T * KTOT
                 + (size_t)(r & 31) * KTOT + c * 8 + k0;
    }
    // W slots: s = jj*256+tid: row=s>>2 in [0,NTILE), chunk c=(s&3)^((s>>3)&3)
    const float* wseg[WSLOT];
    int wslot[WSLOT];
    #pragma unroll
    for (int jj = 0; jj < WSLOT; ++jj) {
        const int s = jj * 256 + tid;
        const int r = s >> 2;
        const int c = (s & 3) ^ ((s >> 3) & 3);
        wseg[jj] = Wf32 + (size_t)e * w_rows * KTOT + (size_t)(n0 + r) * KTOT
                 + c * 8 + k0;
        wslot[jj] = s * 8;
    }

    // fragment read offsets: row r wants chunk quad at pos quad^f(r),
    // f(r) = (r>>1)&3; rows are 16k + l16 -> f = (l16>>1)&3
    const int fx = (l16 >> 1) & 3;
    int aoff[8], boff[NFRAG];
    #pragma unroll
    for (int mt = 0; mt < 8; ++mt)
        aoff[mt] = (mh + mt * 16 + l16) * 32 + ((quad ^ fx) * 8);
    #pragma unroll
    for (int nt = 0; nt < NFRAG; ++nt)
        boff[nt] = (nh + nt * 16 + l16) * 32 + ((quad ^ fx) * 8);

    // prologue: tile 0 in flight
    float4 wr[WSLOT][2];
    #pragma unroll
    for (int jj = 0; jj < WSLOT; ++jj) {
        wr[jj][0] = *(const float4*)(wseg[jj]);
        wr[jj][1] = *(const float4*)(wseg[jj] + 4);
    }
    #pragma unroll
    for (int jj = 0; jj < 4; ++jj)
        async16((char*)sA[0] + (wv * 4 + jj) * 1024, aseg[jj]);

    f32x4 acc[8][NFRAG];
    #pragma unroll
    for (int mt = 0; mt < 8; ++mt)
        #pragma unroll
        for (int nt = 0; nt < NFRAG; ++nt) acc[mt][nt] = {0.f, 0.f, 0.f, 0.f};

    for (int kt = 0; kt < KT; ++kt) {
        const int p = kt & 1;
        // stage W(kt) into LDS (dependency waits its global loads)
        #pragma unroll
        for (int jj = 0; jj < WSLOT; ++jj)
            *(short8*)(sB[p] + wslot[jj]) = cvt8(wr[jj][0], wr[jj][1]);
        __syncthreads();   // drains A-DMA(kt) + publishes W(kt)
        if (kt + 1 < KT) { // prefetch NEXT tile into other buffer
            const int kn = (kt + 1) * 32;
            #pragma unroll
            for (int jj = 0; jj < 4; ++jj)
                async16((char*)sA[1 - p] + (wv * 4 + jj) * 1024, aseg[jj] + kn);
            #pragma unroll
            for (int jj = 0; jj < WSLOT; ++jj) {
                wr[jj][0] = *(const float4*)(wseg[jj] + kn);
                wr[jj][1] = *(const float4*)(wseg[jj] + kn + 4);
            }
        }
        // compute(kt): one 16x16x32 MFMA per (mt,nt) covers the 32-k tile
        short8 wf[NFRAG];
        #pragma unroll
        for (int nt = 0; nt < NFRAG; ++nt)
            wf[nt] = *(const short8*)(sB[p] + boff[nt]);
        #pragma unroll
        for (int mt = 0; mt < 8; ++mt) {
            const short8 af = *(const short8*)(sA[p] + aoff[mt]);
            #pragma unroll
            for (int nt = 0; nt < NFRAG; ++nt)
                acc[mt][nt] = __builtin_amdgcn_mfma_f32_16x16x32_bf16(
                    af, wf[nt], acc[mt][nt], 0, 0, 0);
        }
    }

    // epilogue
    #pragma unroll
    for (int nt = 0; nt < NFRAG; ++nt) {
        const int n = n0 + nh + nt * 16 + l16;
        const float bias = biasb[(size_t)e * w_rows + n];
        #pragma unroll
        for (int mt = 0; mt < 8; ++mt) {
            const int rowb = mh + mt * 16 + quad * 4;
            const int s = rowb >> 5;
            if (s >= cnt) continue;
            const int b = bm[s];
            const float scale = DO_GELU ? 1.0f : beam_w[b];
            #pragma unroll
            for (int r = 0; r < 4; ++r) {
                const int t = (rowb + r) & 31;
                const size_t idx = (size_t)b * T * w_rows + (size_t)t * w_rows + n;
                if (DO_GELU) {
                    float vv = acc[mt][nt][r] + bias;
                    vv = 0.5f * vv * (1.0f + erff(vv * 0.70710678118654752f));
                    ((__hip_bfloat16*)Obase)[idx] = __float2bfloat16(vv);
                } else {
                    // split-K: slices atomically accumulate into zeroed out;
                    // slice 0 carries the bias. Reorder noise ~1e-6 << tol.
                    float vv = acc[mt][nt][r] + ((k0 == 0) ? bias : 0.f);
                    atomicAdd((float*)Obase + idx, vv * scale);
                }
            }
        }
    }
}

extern "C" void kernel_launch(void* const* d_in, const int* in_sizes, int n_in,
                              void* d_out, int out_size, void* d_ws, size_t ws_size,
                              hipStream_t stream)
{
    const float* x      = (const float*)d_in[0];
    const float* gate_w = (const float*)d_in[1];
    const float* w1     = (const float*)d_in[2];
    const float* b1     = (const float*)d_in[3];
    const float* w2     = (const float*)d_in[4];
    const float* b2     = (const float*)d_in[5];
    float* out = (float*)d_out;
    float* ws  = (float*)d_ws;

    float*  logits = ws + WS_LOGITS;
    float*  beam_w = ws + WS_BEAMW;
    int*    sortb  = (int*)(ws + WS_SORT);
    int*    t8e    = (int*)(ws + WS_T8E);
    int*    t8b    = (int*)(ws + WS_T8B);
    int*    t8c    = (int*)(ws + WS_T8C);
    ushort* x_bf   = (ushort*)(ws + WS_XBF);
    ushort* h_bf   = (ushort*)(ws + WS_HBF);

    // zero the main output region (split-K GEMM2 accumulates atomically)
    hipMemsetAsync(out, 0, (size_t)NBEAM * T * H * sizeof(float), stream);

    gate_conv_kernel<<<dim3(3, Bsz), 256, 0, stream>>>(x, gate_w, x_bf, logits);
    gating_kernel<<<1, 64, 0, stream>>>(logits, beam_w, sortb, t8e, t8b, t8c, out);
    // GEMM1 + GELU: M=256/tile, N=DFF in 128-strips, K=768 (24 k-iters)
    moe_ffn_mfma<H, 128, true, 1><<<dim3(DFF / 128, NT8MAX), 256, 0, stream>>>(
        x_bf, NB, w1, DFF, b1, sortb, t8e, t8b, t8c, beam_w, (void*)h_bf);
    // GEMM2 + scale: M=256/tile, N=H in 128-strips, K=3072 split 4x768
    moe_ffn_mfma<DFF, 128, false, 4><<<dim3(H / 128, NT8MAX * 4), 256, 0, stream>>>(
        h_bf, 1, w2, H, b2, sortb, t8e, t8b, t8c, beam_w, out);
}